// Round 8
// baseline (376.169 us; speedup 1.0000x reference)
//
#include <hip/hip_runtime.h>
#include <hip/hip_bf16.h>
#include <math.h>
#include <float.h>

#define B_    32
#define C_    1536
#define T_    2000
#define BOT_  128
#define EPS_  1e-4f

#define CH    64    // c-chunk, phase 1
#define TC    64    // t-chunk per block
#define NTS   32    // ceil(2000/64)

typedef __attribute__((ext_vector_type(8))) short short8;
typedef __attribute__((ext_vector_type(4))) short short4v;
typedef __attribute__((ext_vector_type(4))) float f32x4;

static __device__ __forceinline__ unsigned short f2bf(float f) {
    unsigned u = __float_as_uint(f);
    u += 0x7FFFu + ((u >> 16) & 1u);           // RTNE
    return (unsigned short)(u >> 16);
}

// ---------------------------------------------------------------------------
// K1: per-(b,c) mean and unbiased std over T (fp32 exact).
// ---------------------------------------------------------------------------
__global__ __launch_bounds__(256) void stats_kernel(
    const float* __restrict__ x, float* __restrict__ mean_s, float* __restrict__ std_s) {
    const int row = blockIdx.x;                 // b*C + c
    const float4* x4 = reinterpret_cast<const float4*>(x + (size_t)row * T_);  // 500 vec4
    float s1 = 0.f, s2 = 0.f;
    for (int i = threadIdx.x; i < T_ / 4; i += 256) {
        float4 v = x4[i];
        s1 += v.x + v.y + v.z + v.w;
        s2 = fmaf(v.x, v.x, fmaf(v.y, v.y, fmaf(v.z, v.z, fmaf(v.w, v.w, s2))));
    }
    #pragma unroll
    for (int off = 32; off; off >>= 1) {
        s1 += __shfl_xor(s1, off);
        s2 += __shfl_xor(s2, off);
    }
    __shared__ float ls1[4], ls2[4];
    const int wave = threadIdx.x >> 6, lane = threadIdx.x & 63;
    if (lane == 0) { ls1[wave] = s1; ls2[wave] = s2; }
    __syncthreads();
    if (threadIdx.x == 0) {
        s1 = ls1[0] + ls1[1] + ls1[2] + ls1[3];
        s2 = ls2[0] + ls2[1] + ls2[2] + ls2[3];
        float mean = s1 / (float)T_;
        float var  = (s2 - s1 * mean) / (float)(T_ - 1);
        mean_s[row] = mean;
        std_s[row]  = sqrtf(fmaxf(var, EPS_));
    }
}

// ---------------------------------------------------------------------------
// K1b: convert W1[:, :C] and W2 to bf16.
// ---------------------------------------------------------------------------
__global__ __launch_bounds__(256) void cvt_kernel(
    const float* __restrict__ W1, const float* __restrict__ W2,
    unsigned short* __restrict__ W1b, unsigned short* __restrict__ W2b) {
    int idx = blockIdx.x * 256 + threadIdx.x;
    if (idx < BOT_ * C_) {
        int o = idx / C_, c = idx - o * C_;
        W1b[idx] = f2bf(W1[(size_t)o * (3 * C_) + c]);
        W2b[idx] = f2bf(W2[idx]);
    }
}

// ---------------------------------------------------------------------------
// K2: cb[b][o] = b1[o] + sum_c W1[o][C+c]*mean[b][c] + W1[o][2C+c]*std[b][c]
// ---------------------------------------------------------------------------
__global__ __launch_bounds__(128) void cb_kernel(
    const float* __restrict__ W1, const float* __restrict__ b1,
    const float* __restrict__ mean_s, const float* __restrict__ std_s,
    float* __restrict__ cb) {
    __shared__ float ml[C_];
    __shared__ float sl[C_];
    const int b = blockIdx.x;
    for (int c = threadIdx.x; c < C_; c += 128) {
        ml[c] = mean_s[(size_t)b * C_ + c];
        sl[c] = std_s[(size_t)b * C_ + c];
    }
    __syncthreads();
    const int o = threadIdx.x;
    const float* wm = W1 + (size_t)o * (3 * C_) + C_;
    const float* ws = wm + C_;
    float am0 = 0.f, am1 = 0.f, as0 = 0.f, as1 = 0.f;
    for (int c = 0; c < C_; c += 2) {
        am0 = fmaf(wm[c],     ml[c],     am0);
        am1 = fmaf(wm[c + 1], ml[c + 1], am1);
        as0 = fmaf(ws[c],     sl[c],     as0);
        as1 = fmaf(ws[c + 1], sl[c + 1], as1);
    }
    cb[(size_t)b * BOT_ + o] = b1[o] + (am0 + am1) + (as0 + as1);
}

// ---------------------------------------------------------------------------
// K3 (fused): per (b, 64-t chunk):
//  phase 1: h = relu(W1b.x + cb) via MFMA. Staging: each thread gathers 16
//    fp32 x along c (coalesced per c-row), packs 2x short8, 2 swizzled b128
//    LDS writes (conflict-free). Double-buffered in registers.
//  phase 2: swapped-operand MFMA (A = Hl t-rows, B = W2 c-rows) so lane=c,
//    regs=t: softmax Z/S1/S2 accumulate in-register over t; 2-shfl reduce
//    over g; max-free exp (|L|<~3, b2 cancels). Partials to ws.
// 4 waves, grid (NTS, B). h never touches HBM.
// ---------------------------------------------------------------------------
__global__ __launch_bounds__(256) void fused_main(
    const float* __restrict__ x, const unsigned short* __restrict__ W1b,
    const unsigned short* __restrict__ W2b, const float* __restrict__ cb,
    float* __restrict__ part) {
    const int b   = blockIdx.y;
    const int ts  = blockIdx.x;
    const int t0  = ts * TC;
    const int tid = threadIdx.x;
    const int lane = tid & 63;
    const int w   = tid >> 6;          // 0..3
    const int g   = lane >> 4, li = lane & 15;

    __shared__ __align__(16) unsigned short Xb[64 * 64];    // [t][c] swizzled, 8KB
    __shared__ __align__(16) unsigned short Hl[64 * 128];   // [t][o] swizzled, 16KB

    const float* xb = x + (size_t)b * C_ * T_;

    // ---------------- phase 1 ----------------
    f32x4 hacc[2][4];
    #pragma unroll
    for (int mi = 0; mi < 2; ++mi)
        #pragma unroll
        for (int ni = 0; ni < 4; ++ni)
            hacc[mi][ni] = (f32x4){0.f, 0.f, 0.f, 0.f};

    // staging role: wave w owns c-block [w*16, w*16+16), lane owns t = lane
    const int st_t = lane;
    const int tg_s = t0 + st_t;
    const bool tval = tg_s < T_;

    float xg[16];
    #pragma unroll
    for (int j = 0; j < 16; ++j)
        xg[j] = tval ? xb[(size_t)(w * 16 + j) * T_ + tg_s] : 0.f;

    for (int kc = 0; kc < C_; kc += CH) {
        __syncthreads();   // prior-iter Xb reads complete
        // pack + 2 swizzled b128 writes (slots 2w and 2w+1)
        short8 p0, p1;
        #pragma unroll
        for (int j = 0; j < 8; ++j) {
            p0[j] = (short)f2bf(xg[j]);
            p1[j] = (short)f2bf(xg[8 + j]);
        }
        *reinterpret_cast<short8*>(&Xb[st_t * 64 + (((w * 2 + 0) ^ (st_t & 7)) << 3)]) = p0;
        *reinterpret_cast<short8*>(&Xb[st_t * 64 + (((w * 2 + 1) ^ (st_t & 7)) << 3)]) = p1;
        // prefetch next chunk (in flight during MFMA)
        if (kc + CH < C_) {
            #pragma unroll
            for (int j = 0; j < 16; ++j)
                xg[j] = tval ? xb[(size_t)(kc + CH + w * 16 + j) * T_ + tg_s] : 0.f;
        }
        __syncthreads();
        // wave w owns o-rows [w*32, w*32+32); K=64 in 2 steps of 32
        #pragma unroll
        for (int ks = 0; ks < 2; ++ks) {
            short8 a[2], bb4[4];
            #pragma unroll
            for (int mi = 0; mi < 2; ++mi)
                a[mi] = *reinterpret_cast<const short8*>(
                    W1b + (size_t)(w * 32 + mi * 16 + li) * C_ + kc + ks * 32 + g * 8);
            #pragma unroll
            for (int ni = 0; ni < 4; ++ni)
                bb4[ni] = *reinterpret_cast<const short8*>(
                    &Xb[(ni * 16 + li) * 64 + (((ks * 4 + g) ^ (li & 7)) << 3)]);
            #pragma unroll
            for (int mi = 0; mi < 2; ++mi)
                #pragma unroll
                for (int ni = 0; ni < 4; ++ni)
                    hacc[mi][ni] = __builtin_amdgcn_mfma_f32_16x16x32_bf16(a[mi], bb4[ni], hacc[mi][ni], 0, 0, 0);
        }
    }

    // epilogue: +cb, relu, bf16 -> Hl[t][o] (swizzled, 8B writes)
    __syncthreads();
    #pragma unroll
    for (int mi = 0; mi < 2; ++mi) {
        const int ob = w * 32 + mi * 16 + g * 4;
        const float4 cbv = *reinterpret_cast<const float4*>(cb + (size_t)b * BOT_ + ob);
        #pragma unroll
        for (int ni = 0; ni < 4; ++ni) {
            int t = ni * 16 + li;
            short4v pk;
            pk[0] = (short)f2bf(fmaxf(hacc[mi][ni][0] + cbv.x, 0.f));
            pk[1] = (short)f2bf(fmaxf(hacc[mi][ni][1] + cbv.y, 0.f));
            pk[2] = (short)f2bf(fmaxf(hacc[mi][ni][2] + cbv.z, 0.f));
            pk[3] = (short)f2bf(fmaxf(hacc[mi][ni][3] + cbv.w, 0.f));
            *reinterpret_cast<short4v*>(
                &Hl[t * 128 + (((w * 4 + mi * 2 + (g >> 1)) ^ (t & 7)) << 3) + (g & 1) * 4]) = pk;
        }
    }
    __syncthreads();

    // ---------------- phase 2: swapped MFMA, lane = c ----------------
    float* pbase = part + (((size_t)b * NTS + ts) * 3) * C_;

    for (int ccb = 0; ccb < C_; ccb += 64) {
        const int c = ccb + w * 16 + li;
        // x fp32 loads for weighted sums (L2-warm; float4 per ni)
        f32x4 xv[4];
        #pragma unroll
        for (int ni = 0; ni < 4; ++ni) {
            const int tg = t0 + ni * 16 + g * 4;
            const float* xp = xb + (size_t)c * T_ + tg;
            if (tg + 4 <= T_) {
                xv[ni] = *reinterpret_cast<const f32x4*>(xp);
            } else {
                #pragma unroll
                for (int r = 0; r < 4; ++r)
                    xv[ni][r] = (tg + r < T_) ? xp[r] : 0.f;
            }
        }
        // B-frags: W2b rows c (k = o contiguous)
        short8 bfr[4];
        #pragma unroll
        for (int ks = 0; ks < 4; ++ks)
            bfr[ks] = *reinterpret_cast<const short8*>(
                W2b + (size_t)c * BOT_ + ks * 32 + g * 8);
        // logits: D[t][c], t in regs, c = lane
        f32x4 lacc[4];
        #pragma unroll
        for (int ni = 0; ni < 4; ++ni) lacc[ni] = (f32x4){0.f, 0.f, 0.f, 0.f};
        #pragma unroll
        for (int ks = 0; ks < 4; ++ks) {
            short8 af[4];
            #pragma unroll
            for (int ni = 0; ni < 4; ++ni)
                af[ni] = *reinterpret_cast<const short8*>(
                    &Hl[(ni * 16 + li) * 128 + (((ks * 4 + g) ^ (li & 7)) << 3)]);
            #pragma unroll
            for (int ni = 0; ni < 4; ++ni)
                lacc[ni] = __builtin_amdgcn_mfma_f32_16x16x32_bf16(af[ni], bfr[ks], lacc[ni], 0, 0, 0);
        }
        // max-free exp + in-register t-accumulation
        float Z = 0.f, S1 = 0.f, S2 = 0.f;
        #pragma unroll
        for (int ni = 0; ni < 4; ++ni)
            #pragma unroll
            for (int r = 0; r < 4; ++r) {
                int t = t0 + ni * 16 + g * 4 + r;
                float p = __expf(lacc[ni][r]);
                p = (t < T_) ? p : 0.f;
                float xx = xv[ni][r];
                Z += p;
                S1 = fmaf(xx, p, S1);
                S2 = fmaf(xx * xx, p, S2);
            }
        // reduce across g (lanes ^16, ^32)
        Z  += __shfl_xor(Z, 16);  Z  += __shfl_xor(Z, 32);
        S1 += __shfl_xor(S1, 16); S1 += __shfl_xor(S1, 32);
        S2 += __shfl_xor(S2, 16); S2 += __shfl_xor(S2, 32);
        if (lane < 16) {
            pbase[c]          = Z;
            pbase[C_ + c]     = S1;
            pbase[2 * C_ + c] = S2;
        }
    }
}

// ---------------------------------------------------------------------------
// K4: fold the NTS t-chunk partials, finalize wmean/wsd.
// ---------------------------------------------------------------------------
__global__ __launch_bounds__(256) void reduce_kernel(
    const float* __restrict__ part, float* __restrict__ out) {
    const int c = blockIdx.x * 256 + threadIdx.x;
    const int b = blockIdx.y;
    float Z = 0.f, S1 = 0.f, S2 = 0.f;
    for (int ts = 0; ts < NTS; ++ts) {
        const float* pb = part + (((size_t)b * NTS + ts) * 3) * C_ + c;
        Z  += pb[0];
        S1 += pb[C_];
        S2 += pb[2 * C_];
    }
    float wmean = S1 / Z;
    float wsd   = sqrtf(fmaxf(S2 / Z - wmean * wmean, EPS_));
    out[(size_t)b * (2 * C_) + c]      = wmean;
    out[(size_t)b * (2 * C_) + C_ + c] = wsd;
}

// ---------------------------------------------------------------------------
extern "C" void kernel_launch(void* const* d_in, const int* in_sizes, int n_in,
                              void* d_out, int out_size, void* d_ws, size_t ws_size,
                              hipStream_t stream) {
    const float* x  = (const float*)d_in[0];   // [B, C, T]
    const float* W1 = (const float*)d_in[1];   // [BOT, 3C]
    const float* b1 = (const float*)d_in[2];   // [BOT]
    const float* W2 = (const float*)d_in[3];   // [C, BOT]
    // b2 (d_in[4]) cancels in softmax over T
    float* out = (float*)d_out;                // [B, 2C]

    float* ws = (float*)d_ws;
    float* mean_s = ws;                                   // B*C
    float* std_s  = mean_s + (size_t)B_ * C_;             // B*C
    float* cb     = std_s  + (size_t)B_ * C_;             // B*BOT
    float* part   = cb + (size_t)B_ * BOT_;               // B*NTS*3*C (18.9MB)
    unsigned short* W1b = (unsigned short*)(part + (size_t)B_ * NTS * 3 * C_);
    unsigned short* W2b = W1b + (size_t)BOT_ * C_;        // C*BOT

    stats_kernel<<<dim3(B_ * C_), 256, 0, stream>>>(x, mean_s, std_s);
    cvt_kernel<<<dim3((BOT_ * C_ + 255) / 256), 256, 0, stream>>>(W1, W2, W1b, W2b);
    cb_kernel<<<dim3(B_), 128, 0, stream>>>(W1, b1, mean_s, std_s, cb);
    fused_main<<<dim3(NTS, B_), 256, 0, stream>>>(x, W1b, W2b, cb, part);
    reduce_kernel<<<dim3(C_ / 256, B_), 256, 0, stream>>>(part, out);
}